// Round 4
// baseline (86.253 us; speedup 1.0000x reference)
//
#include <hip/hip_runtime.h>
#include <math.h>

#define B_ROWS 4096
#define DIM 128
#define LBL 100
#define NCHUNK 16   // column chunks of 256
#define NTILE 32    // row tiles of 128

typedef __attribute__((ext_vector_type(8))) short bf16x8;
typedef __attribute__((ext_vector_type(4))) float f32x4;

__device__ __forceinline__ unsigned f2bf(float x) {
  union { float f; unsigned u; } a; a.f = x;
  unsigned r = a.u + 0x7fffu + ((a.u >> 16) & 1u);  // RNE
  return r >> 16;
}

// async global->LDS DMA, 16B per lane; LDS dest = wave-uniform base + lane*16
__device__ __forceinline__ void lds_dma16(void* l, const void* g) {
  __builtin_amdgcn_global_load_lds(
      (const __attribute__((address_space(1))) void*)g,
      (__attribute__((address_space(3))) void*)l, 16, 0, 0);
}

// cf: bf16(view0 features), stored XOR-swizzled per 128-row tile:
// chunk (r,kc) of tile t lives at cf[t*2048 + kc*128 + (r^kc)] (uint4 = 8 bf16).
// One thread per 16B chunk; writes fully coalesced, reads 32B-granule gather.
__global__ void pack_kernel(const float* __restrict__ feat,
                            uint4* __restrict__ cf) {
  int g = blockIdx.x * 256 + threadIdx.x;  // global chunk id, 65536 total
  int tile = g >> 11, o = g & 2047;
  int kc = o >> 7, q = o & 127;
  int r = q ^ kc;                          // inverse of the swizzle
  const float* src = feat + ((size_t)(tile * 128 + r)) * 256 + kc * 8;  // view0
  float4 a = *(const float4*)src;
  float4 b = *(const float4*)(src + 4);
  uint4 ov;
  ov.x = f2bf(a.x) | (f2bf(a.y) << 16);
  ov.y = f2bf(a.z) | (f2bf(a.w) << 16);
  ov.z = f2bf(b.x) | (f2bf(b.y) << 16);
  ov.w = f2bf(b.z) | (f2bf(b.w) << 16);
  cf[g] = ov;
}

// One wave per row: 128-bit label mask + row sum + seedRaw = sum(bf16(f)^2) - slack.
// seedRaw is a lower bound on the row's raw diagonal MFMA dot (reassoc err ~1e-3).
__global__ void seedlabel_kernel(const float* __restrict__ feat,
                                 const float* __restrict__ labels,
                                 uint4* __restrict__ Lb,
                                 int* __restrict__ rsv,
                                 float* __restrict__ seedRaw) {
  int w = (int)((blockIdx.x * blockDim.x + threadIdx.x) >> 6);
  int lane = threadIdx.x & 63;
  const float2* src = (const float2*)(feat + (size_t)w * 256);  // view0 row
  float2 f = src[lane];
  float b0 = __uint_as_float(f2bf(f.x) << 16);
  float b1 = __uint_as_float(f2bf(f.y) << 16);
  float s = b0 * b0 + b1 * b1;
  #pragma unroll
  for (int off = 32; off >= 1; off >>= 1) s += __shfl_xor(s, off);
  float x0 = labels[(size_t)w * LBL + lane];
  float x1 = (lane < LBL - 64) ? labels[(size_t)w * LBL + 64 + lane] : 0.0f;
  unsigned long long m0 = __ballot(x0 != 0.0f);
  unsigned long long m1 = __ballot(x1 != 0.0f);
  if (lane == 0) {
    Lb[w] = make_uint4((unsigned)m0, (unsigned)(m0 >> 32),
                       (unsigned)m1, (unsigned)(m1 >> 32));
    rsv[w] = __popcll(m0) + __popcll(m1);
    seedRaw[w] = s - 0.15f;  // 0.15 raw = 2.1 logits slack >> 1e-3 reassoc err
  }
}

// C = cf @ cf^T (raw dots; *invT in epilogue). logits_max cancels in
// -log(p/(p+n)), so only the BxB left block is needed and p,n accumulate
// relative to the fixed per-row seed (max exp arg ~ +2.2). Terms below
// seed-6.3 raw (= 90 logits) underflow to 0 in the reference's fp32 sums too.
__launch_bounds__(256, 2)
__global__ void main_kernel(const uint4* __restrict__ cf,
                            const uint4* __restrict__ Lb,
                            const int* __restrict__ rsv,
                            const float* __restrict__ seedRaw,
                            float2* __restrict__ part) {
  __shared__ uint4 As[2048];  // 32 KB, pre-swizzled tile
  __shared__ uint4 Bs[2048];  // 32 KB
  const int tid = threadIdx.x;
  const int lane = tid & 63;
  const int l15 = lane & 15;
  const int quad = lane >> 4;
  const int wave = tid >> 6;
  const int wi = (wave & 1) * 64;   // wave row offset in 128
  const int wj = (wave >> 1) * 64;  // wave col offset in 128
  const int rowBase = blockIdx.x * 128;
  const float invT = 1.0f / 0.07f;

  // issue A staging DMA (drains at the first __syncthreads inside the loop)
  #pragma unroll
  for (int it = 0; it < 8; ++it) {
    int flat = it * 256 + tid;
    lds_dma16(&As[flat], &cf[(size_t)blockIdx.x * 2048 + flat]);
  }

  float srow[16], p_s[16], n_s[16];
  #pragma unroll
  for (int ti = 0; ti < 4; ++ti)
    #pragma unroll
    for (int r = 0; r < 4; ++r) {
      srow[ti * 4 + r] = seedRaw[rowBase + wi + ti * 16 + quad * 4 + r];
      p_s[ti * 4 + r] = 0.f;
      n_s[ti * 4 + r] = 0.f;
    }

  const bf16x8* Asv = (const bf16x8*)As;
  const bf16x8* Bsv = (const bf16x8*)Bs;

  for (int jt = 0; jt < 2; ++jt) {
    const int colBase = blockIdx.y * 256 + jt * 128;
    __syncthreads();  // previous compute done -> Bs reusable
    #pragma unroll
    for (int it = 0; it < 8; ++it) {
      int flat = it * 256 + tid;
      lds_dma16(&Bs[flat], &cf[(size_t)(colBase >> 7) * 2048 + flat]);
    }
    __syncthreads();  // all waves' DMA drained

    // prefetch column label masks (consumed only by the rare diag slow path;
    // latency hidden under the MFMA loop)
    uint4 clb[4];
    int crs[4];
    #pragma unroll
    for (int tj = 0; tj < 4; ++tj) {
      int gcol = colBase + wj + tj * 16 + l15;
      clb[tj] = Lb[gcol];
      crs[tj] = rsv[gcol];
    }

    f32x4 acc[4][4];
    #pragma unroll
    for (int ti = 0; ti < 4; ++ti)
      #pragma unroll
      for (int tj = 0; tj < 4; ++tj)
        acc[ti][tj] = (f32x4){0.f, 0.f, 0.f, 0.f};

    #pragma unroll
    for (int ks = 0; ks < 4; ++ks) {
      const int kc = ks * 4 + quad;
      const int abase = kc * 128 + wi + (l15 ^ kc);
      const int bbase = kc * 128 + wj + (l15 ^ kc);
      bf16x8 af[4], bfr[4];
      #pragma unroll
      for (int t = 0; t < 4; ++t) {
        af[t] = Asv[abase + t * 16];
        bfr[t] = Bsv[bbase + t * 16];
      }
      #pragma unroll
      for (int ti = 0; ti < 4; ++ti)
        #pragma unroll
        for (int tj = 0; tj < 4; ++tj)
          acc[ti][tj] = __builtin_amdgcn_mfma_f32_16x16x32_bf16(
              af[ti], bfr[tj], acc[ti][tj], 0, 0, 0);
    }

    // epilogue: C[row][col] raw dots; row=wi+ti*16+quad*4+r, col=wj+tj*16+l15
    #pragma unroll
    for (int ti = 0; ti < 4; ++ti)
      #pragma unroll
      for (int r = 0; r < 4; ++r) {
        int si = ti * 4 + r;
        float l0 = acc[ti][0][r], l1 = acc[ti][1][r];
        float l2 = acc[ti][2][r], l3 = acc[ti][3][r];
        float tm = fmaxf(fmaxf(l0, l1), fmaxf(l2, l3));
        if (tm > srow[si] - 6.3f) {  // survives exp vs diag reference
          int grow = rowBase + wi + ti * 16 + quad * 4 + r;
          uint4 la = Lb[grow];
          int ra = rsv[grow];
          float p = p_s[si], n = n_s[si];
          float lv[4] = {l0, l1, l2, l3};
          #pragma unroll
          for (int tj = 0; tj < 4; ++tj) {
            float e = __expf((lv[tj] - srow[si]) * invT);
            int inter = __popc(la.x & clb[tj].x) + __popc(la.y & clb[tj].y) +
                        __popc(la.z & clb[tj].z) + __popc(la.w & clb[tj].w);
            if (3 * inter > ra + crs[tj]) p += e; else n += e;  // sim>=0.5 exact
          }
          p_s[si] = p;
          n_s[si] = n;
        }
      }
  }

  // plain sums across the 16 lanes (same quad) sharing each row
  #pragma unroll
  for (int si = 0; si < 16; ++si) {
    float p = p_s[si], n = n_s[si];
    #pragma unroll
    for (int off = 8; off >= 1; off >>= 1) {
      p += __shfl_xor(p, off);
      n += __shfl_xor(n, off);
    }
    p_s[si] = p;
    n_s[si] = n;
  }

  // merge the two waves sharing each row (wj=0 / wj=64) via LDS, then store
  __syncthreads();
  float* mbuf = (float*)As;
  if (wj == 64 && l15 == 0) {
    #pragma unroll
    for (int ti = 0; ti < 4; ++ti)
      #pragma unroll
      for (int r = 0; r < 4; ++r) {
        int row = wi + ti * 16 + quad * 4 + r;
        int si = ti * 4 + r;
        mbuf[row * 2 + 0] = p_s[si];
        mbuf[row * 2 + 1] = n_s[si];
      }
  }
  __syncthreads();
  if (wj == 0 && l15 == 0) {
    #pragma unroll
    for (int ti = 0; ti < 4; ++ti)
      #pragma unroll
      for (int r = 0; r < 4; ++r) {
        int row = wi + ti * 16 + quad * 4 + r;
        int si = ti * 4 + r;
        float p = p_s[si] + mbuf[row * 2 + 0];
        float n = n_s[si] + mbuf[row * 2 + 1];
        part[(size_t)blockIdx.y * B_ROWS + rowBase + row] = make_float2(p, n);
      }
  }
}

// single block: sum chunks, per-row loss, block reduction, final divide
__global__ void mergefin_kernel(const float2* __restrict__ part,
                                const int* __restrict__ rsv,
                                float* __restrict__ out) {
  __shared__ float red[8];
  int t = threadIdx.x;
  float per = 0.f, cnt = 0.f;
  #pragma unroll
  for (int i = 0; i < 16; ++i) {
    int row = i * 256 + t;
    float p = 0.f, n = 0.f;
    #pragma unroll
    for (int c = 0; c < NCHUNK; ++c) {
      float2 v = part[(size_t)c * B_ROWS + row];
      p += v.x;
      n += v.y;
    }
    if (rsv[row] > 0) {  // exact: has_pos <=> row_sum > 0
      per += -logf(p / (p + n));
      cnt += 1.f;
    }
  }
  #pragma unroll
  for (int off = 32; off >= 1; off >>= 1) {
    per += __shfl_xor(per, off);
    cnt += __shfl_xor(cnt, off);
  }
  int wv = t >> 6;
  if ((t & 63) == 0) { red[wv * 2] = per; red[wv * 2 + 1] = cnt; }
  __syncthreads();
  if (t == 0) {
    float P = red[0] + red[2] + red[4] + red[6];
    float C = red[1] + red[3] + red[5] + red[7];
    out[0] = P / fmaxf(C, 1.0f);
  }
}

extern "C" void kernel_launch(void* const* d_in, const int* in_sizes, int n_in,
                              void* d_out, int out_size, void* d_ws, size_t ws_size,
                              hipStream_t stream) {
  const float* feat = (const float*)d_in[0];
  const float* labels = (const float*)d_in[1];
  float* out = (float*)d_out;
  char* ws = (char*)d_ws;
  // workspace layout (~1.6 MB):
  uint4* cf = (uint4*)(ws + 0);                    // 1 MB  swizzled bf16 view0
  uint4* Lbm = (uint4*)(ws + 1048576);             // 64 KB label masks
  int* rsv = (int*)(ws + 1114112);                 // 16 KB row sums
  float* seedRaw = (float*)(ws + 1130496);         // 16 KB diag seeds
  float2* part = (float2*)(ws + 1146880);          // 512 KB partials

  hipLaunchKernelGGL(pack_kernel, dim3(256), dim3(256), 0, stream, feat, cf);
  hipLaunchKernelGGL(seedlabel_kernel, dim3(1024), dim3(256), 0, stream,
                     feat, labels, Lbm, rsv, seedRaw);
  hipLaunchKernelGGL(main_kernel, dim3(NTILE, NCHUNK), dim3(256), 0, stream,
                     cf, Lbm, rsv, seedRaw, part);
  hipLaunchKernelGGL(mergefin_kernel, dim3(1), dim3(256), 0, stream,
                     part, rsv, out);
}

// Round 5
// 85.006 us; speedup vs baseline: 1.0147x; 1.0147x over previous
//
#include <hip/hip_runtime.h>
#include <math.h>

#define B_ROWS 4096
#define DIM 128
#define LBL 100
#define NCT 32   // 32x32 grid of 128x128 C tiles

typedef __attribute__((ext_vector_type(8))) short bf16x8;
typedef __attribute__((ext_vector_type(4))) float f32x4;

__device__ __forceinline__ unsigned f2bf(float x) {
  union { float f; unsigned u; } a; a.f = x;
  unsigned r = a.u + 0x7fffu + ((a.u >> 16) & 1u);  // RNE
  return r >> 16;
}

// async global->LDS DMA, 16B/lane; LDS dest = wave-uniform base + lane*16
__device__ __forceinline__ void lds_dma16(void* l, const void* g) {
  __builtin_amdgcn_global_load_lds(
      (const __attribute__((address_space(1))) void*)g,
      (__attribute__((address_space(3))) void*)l, 16, 0, 0);
}

// cf: bf16(view0), XOR-swizzled per 128-row tile: logical chunk (r,kc) of tile
// t lives at cf[t*2048 + kc*128 + (r^kc)]. Reads fully coalesced (consecutive
// threads sweep one row's 128 floats); 16B writes scatter within the tile (L2).
// Block 0 also zeroes the loss accumulator.
__global__ void pack_kernel(const float* __restrict__ feat,
                            uint4* __restrict__ cf,
                            float* __restrict__ accum) {
  if (blockIdx.x == 0 && threadIdx.x < 2) accum[threadIdx.x] = 0.0f;
  int g = blockIdx.x * 256 + threadIdx.x;  // chunk id, 65536 total
  int tile = g >> 11, rem = g & 2047;
  int r = rem >> 4, kc = rem & 15;
  const float* src = feat + ((size_t)(tile * 128 + r)) * 256 + kc * 8;  // view0
  float4 a = *(const float4*)src;
  float4 b = *(const float4*)(src + 4);
  uint4 ov;
  ov.x = f2bf(a.x) | (f2bf(a.y) << 16);
  ov.y = f2bf(a.z) | (f2bf(a.w) << 16);
  ov.z = f2bf(b.x) | (f2bf(b.y) << 16);
  ov.w = f2bf(b.z) | (f2bf(b.w) << 16);
  cf[(size_t)tile * 2048 + kc * 128 + (r ^ kc)] = ov;
}

// One wave per row: 128-bit label mask, row sum, seedRaw = sum(bf16(f)^2)-slack
// (lower bound on the raw diagonal MFMA dot; reassoc err ~1e-3 << 0.15 slack).
__global__ void seedlabel_kernel(const float* __restrict__ feat,
                                 const float* __restrict__ labels,
                                 uint4* __restrict__ Lb,
                                 int* __restrict__ rsv,
                                 float* __restrict__ seedRaw) {
  int w = (int)((blockIdx.x * blockDim.x + threadIdx.x) >> 6);
  int lane = threadIdx.x & 63;
  const float2* src = (const float2*)(feat + (size_t)w * 256);  // view0 row
  float2 f = src[lane];
  float b0 = __uint_as_float(f2bf(f.x) << 16);
  float b1 = __uint_as_float(f2bf(f.y) << 16);
  float s = b0 * b0 + b1 * b1;
  #pragma unroll
  for (int off = 32; off >= 1; off >>= 1) s += __shfl_xor(s, off);
  float x0 = labels[(size_t)w * LBL + lane];
  float x1 = (lane < LBL - 64) ? labels[(size_t)w * LBL + 64 + lane] : 0.0f;
  unsigned long long m0 = __ballot(x0 != 0.0f);
  unsigned long long m1 = __ballot(x1 != 0.0f);
  if (lane == 0) {
    Lb[w] = make_uint4((unsigned)m0, (unsigned)(m0 >> 32),
                       (unsigned)m1, (unsigned)(m1 >> 32));
    rsv[w] = __popcll(m0) + __popcll(m1);
    seedRaw[w] = s - 0.15f;  // 0.15 raw = 2.1 logit slack
  }
}

// One 128x128 C tile per block (raw dots, *invT in epilogue). logits_max
// cancels in -log(p/(p+n)); terms below seed-6.3 raw (=92 logits below the
// diag logit) underflow to exactly 0 in the reference's fp32 sums too.
// All metadata staged coalesced into LDS: zero scattered global gathers.
__launch_bounds__(256, 2)
__global__ void main_kernel(const uint4* __restrict__ cf,
                            const uint4* __restrict__ Lb,
                            const int* __restrict__ rsv,
                            const float* __restrict__ seedRaw,
                            float2* __restrict__ part) {
  __shared__ uint4 As[2048];   // 32 KB pre-swizzled row tile
  __shared__ uint4 Bs[2048];   // 32 KB pre-swizzled col tile
  __shared__ uint4 cLb[128];   // col label masks
  __shared__ uint4 rLb[128];   // row label masks
  __shared__ int   cRs[128];
  __shared__ int   rRs[128];
  __shared__ float sS[128];    // row seeds
  const int tid = threadIdx.x;
  const int lane = tid & 63;
  const int l15 = lane & 15;
  const int quad = lane >> 4;
  const int wave = tid >> 6;
  const int wi = (wave & 1) * 64;   // wave row offset in 128
  const int wj = (wave >> 1) * 64;  // wave col offset in 128
  const int rowBase = blockIdx.x * 128;
  const int colBase = blockIdx.y * 128;
  const float invT = 1.0f / 0.07f;

  // issue ALL staging DMA up front (16 in flight/lane), then metadata
  #pragma unroll
  for (int it = 0; it < 8; ++it) {
    int flat = it * 256 + tid;
    lds_dma16(&As[flat], &cf[(size_t)blockIdx.x * 2048 + flat]);
    lds_dma16(&Bs[flat], &cf[(size_t)blockIdx.y * 2048 + flat]);
  }
  if (tid < 128) {
    cLb[tid] = Lb[colBase + tid];
    cRs[tid] = rsv[colBase + tid];
    sS[tid] = seedRaw[rowBase + tid];
  } else {
    int t = tid - 128;
    rLb[t] = Lb[rowBase + t];
    rRs[t] = rsv[rowBase + t];
  }
  __syncthreads();  // drains DMA (vmcnt) + metadata (lgkmcnt)

  float srow[16];
  #pragma unroll
  for (int ti = 0; ti < 4; ++ti)
    #pragma unroll
    for (int r = 0; r < 4; ++r)
      srow[ti * 4 + r] = sS[wi + ti * 16 + quad * 4 + r];

  const bf16x8* Asv = (const bf16x8*)As;
  const bf16x8* Bsv = (const bf16x8*)Bs;

  f32x4 acc[4][4];
  #pragma unroll
  for (int ti = 0; ti < 4; ++ti)
    #pragma unroll
    for (int tj = 0; tj < 4; ++tj)
      acc[ti][tj] = (f32x4){0.f, 0.f, 0.f, 0.f};

  #pragma unroll
  for (int ks = 0; ks < 4; ++ks) {
    const int kc = ks * 4 + quad;
    const int abase = kc * 128 + wi + (l15 ^ kc);
    const int bbase = kc * 128 + wj + (l15 ^ kc);
    bf16x8 af[4], bfr[4];
    #pragma unroll
    for (int t = 0; t < 4; ++t) {
      af[t] = Asv[abase + t * 16];
      bfr[t] = Bsv[bbase + t * 16];
    }
    #pragma unroll
    for (int ti = 0; ti < 4; ++ti)
      #pragma unroll
      for (int tj = 0; tj < 4; ++tj)
        acc[ti][tj] = __builtin_amdgcn_mfma_f32_16x16x32_bf16(
            af[ti], bfr[tj], acc[ti][tj], 0, 0, 0);
  }

  // epilogue: C[row][col], row(local)=wi+ti*16+quad*4+r, col(local)=wj+tj*16+l15
  float p_s[16], n_s[16];
  #pragma unroll
  for (int i = 0; i < 16; ++i) { p_s[i] = 0.f; n_s[i] = 0.f; }
  #pragma unroll
  for (int ti = 0; ti < 4; ++ti)
    #pragma unroll
    for (int r = 0; r < 4; ++r) {
      int si = ti * 4 + r;
      float l0 = acc[ti][0][r], l1 = acc[ti][1][r];
      float l2 = acc[ti][2][r], l3 = acc[ti][3][r];
      float tm = fmaxf(fmaxf(l0, l1), fmaxf(l2, l3));
      if (tm > srow[si] - 6.3f) {  // survives exp vs diag reference (rare)
        int lrow = wi + ti * 16 + quad * 4 + r;
        uint4 la = rLb[lrow];
        int ra = rRs[lrow];
        float p = 0.f, n = 0.f;
        float lv[4] = {l0, l1, l2, l3};
        #pragma unroll
        for (int tj = 0; tj < 4; ++tj) {
          float e = __expf((lv[tj] - srow[si]) * invT);
          int lcol = wj + tj * 16 + l15;
          uint4 lb = cLb[lcol];
          int inter = __popc(la.x & lb.x) + __popc(la.y & lb.y) +
                      __popc(la.z & lb.z) + __popc(la.w & lb.w);
          if (3 * inter > ra + cRs[lcol]) p += e; else n += e;  // sim>=0.5 exact
        }
        p_s[si] = p;
        n_s[si] = n;
      }
    }

  // sum across the 16 lanes (same quad) sharing each row
  #pragma unroll
  for (int si = 0; si < 16; ++si) {
    float p = p_s[si], n = n_s[si];
    #pragma unroll
    for (int off = 8; off >= 1; off >>= 1) {
      p += __shfl_xor(p, off);
      n += __shfl_xor(n, off);
    }
    p_s[si] = p;
    n_s[si] = n;
  }

  // merge the two waves sharing each row (wj=0 / wj=64) via LDS, then store
  __syncthreads();
  float* mbuf = (float*)As;  // As dead; reuse
  if (wj == 64 && l15 == 0) {
    #pragma unroll
    for (int ti = 0; ti < 4; ++ti)
      #pragma unroll
      for (int r = 0; r < 4; ++r) {
        int row = wi + ti * 16 + quad * 4 + r;
        int si = ti * 4 + r;
        mbuf[row * 2 + 0] = p_s[si];
        mbuf[row * 2 + 1] = n_s[si];
      }
  }
  __syncthreads();
  if (wj == 0 && l15 == 0) {
    #pragma unroll
    for (int ti = 0; ti < 4; ++ti)
      #pragma unroll
      for (int r = 0; r < 4; ++r) {
        int row = wi + ti * 16 + quad * 4 + r;
        int si = ti * 4 + r;
        float p = p_s[si] + mbuf[row * 2 + 0];
        float n = n_s[si] + mbuf[row * 2 + 1];
        part[(size_t)blockIdx.y * B_ROWS + rowBase + row] = make_float2(p, n);
      }
  }
}

// 16 blocks x 256: one row per thread, 32 coalesced chunk loads, per-row loss,
// wave reduction, one atomic per wave.
__global__ void merge_kernel(const float2* __restrict__ part,
                             const int* __restrict__ rsv,
                             float* __restrict__ accum) {
  int row = blockIdx.x * 256 + threadIdx.x;
  float p = 0.f, n = 0.f;
  #pragma unroll
  for (int c = 0; c < NCT; ++c) {
    float2 v = part[(size_t)c * B_ROWS + row];
    p += v.x;
    n += v.y;
  }
  float per = 0.f, cnt = 0.f;
  if (rsv[row] > 0) {  // exact: has_pos <=> row_sum > 0
    per = -logf(p / (p + n));
    cnt = 1.f;
  }
  #pragma unroll
  for (int off = 32; off >= 1; off >>= 1) {
    per += __shfl_xor(per, off);
    cnt += __shfl_xor(cnt, off);
  }
  if ((threadIdx.x & 63) == 0) {
    atomicAdd(accum + 0, per);
    atomicAdd(accum + 1, cnt);
  }
}

__global__ void fin_kernel(const float* __restrict__ accum,
                           float* __restrict__ out) {
  out[0] = accum[0] / fmaxf(accum[1], 1.0f);
}

extern "C" void kernel_launch(void* const* d_in, const int* in_sizes, int n_in,
                              void* d_out, int out_size, void* d_ws, size_t ws_size,
                              hipStream_t stream) {
  const float* feat = (const float*)d_in[0];
  const float* labels = (const float*)d_in[1];
  float* out = (float*)d_out;
  char* ws = (char*)d_ws;
  // workspace layout (~2.1 MB):
  uint4* cf = (uint4*)(ws + 0);                    // 1 MB swizzled bf16 view0
  uint4* Lbm = (uint4*)(ws + 1048576);             // 64 KB label masks
  int* rsv = (int*)(ws + 1114112);                 // 16 KB row sums
  float* seedRaw = (float*)(ws + 1130496);         // 16 KB diag seeds
  float2* part = (float2*)(ws + 1146880);          // 1 MB partials (32 x 4096)
  float* accum = (float*)(ws + 1146880 + 1048576); // 8 B

  hipLaunchKernelGGL(pack_kernel, dim3(256), dim3(256), 0, stream,
                     feat, cf, accum);
  hipLaunchKernelGGL(seedlabel_kernel, dim3(1024), dim3(256), 0, stream,
                     feat, labels, Lbm, rsv, seedRaw);
  hipLaunchKernelGGL(main_kernel, dim3(NCT, NCT), dim3(256), 0, stream,
                     cf, Lbm, rsv, seedRaw, part);
  hipLaunchKernelGGL(merge_kernel, dim3(B_ROWS / 256), dim3(256), 0, stream,
                     part, rsv, accum);
  hipLaunchKernelGGL(fin_kernel, dim3(1), dim3(1), 0, stream, accum, out);
}

// Round 6
// 82.945 us; speedup vs baseline: 1.0399x; 1.0248x over previous
//
#include <hip/hip_runtime.h>
#include <math.h>

#define B_ROWS 4096
#define LBL 100
#define NCT 32     // 32x32 tile grid, upper triangle only
#define NTRI 528   // 32*33/2 blocks

typedef __attribute__((ext_vector_type(8))) short bf16x8;
typedef __attribute__((ext_vector_type(4))) float f32x4;

__device__ __forceinline__ unsigned f2bf(float x) {
  union { float f; unsigned u; } a; a.f = x;
  unsigned r = a.u + 0x7fffu + ((a.u >> 16) & 1u);  // RNE
  return r >> 16;
}
__device__ __forceinline__ float bf2f(unsigned h) {
  return __uint_as_float(h << 16);
}

// One wave per row: 128-bit label mask + row sum. Block 0 zeroes accum.
__global__ void label_kernel(const float* __restrict__ labels,
                             uint4* __restrict__ Lb,
                             int* __restrict__ rsv,
                             float* __restrict__ accum) {
  if (blockIdx.x == 0 && threadIdx.x < 2) accum[threadIdx.x] = 0.0f;
  int w = (int)((blockIdx.x * blockDim.x + threadIdx.x) >> 6);
  int lane = threadIdx.x & 63;
  float x0 = labels[(size_t)w * LBL + lane];
  float x1 = (lane < LBL - 64) ? labels[(size_t)w * LBL + 64 + lane] : 0.0f;
  unsigned long long m0 = __ballot(x0 != 0.0f);
  unsigned long long m1 = __ballot(x1 != 0.0f);
  if (lane == 0) {
    Lb[w] = make_uint4((unsigned)m0, (unsigned)(m0 >> 32),
                       (unsigned)m1, (unsigned)(m1 >> 32));
    rsv[w] = __popcll(m0) + __popcll(m1);
  }
}

// Self-contained: one upper-triangle 128x128 tile per block. Stages fp32 feat
// directly (f2bf in VGPR -> swizzled LDS), computes per-row/col exp references
// in-block (bit-identical across blocks: same inputs, same op order), MFMA raw
// dots, fast-path epilogue, row-side AND col-side partials (symmetry).
// logits_max cancels in -log(p/(p+n)); terms below ref-6.3 raw (=90 logits
// under the diag logit) underflow to 0 in the reference's fp32 sums too.
__launch_bounds__(256, 2)
__global__ void main_kernel(const float* __restrict__ feat,
                            const uint4* __restrict__ Lb,
                            const int* __restrict__ rsv,
                            float2* __restrict__ part) {
  __shared__ uint4 As[2048];   // 32 KB bf16 row tile, XOR-swizzled chunks
  __shared__ uint4 Bs[2048];   // 32 KB bf16 col tile
  __shared__ uint4 rLbS[128], cLbS[128];
  __shared__ int rRsS[128], cRsS[128];
  __shared__ float sS[128], sB[128];  // row / col exp references

  // triangular decode: bid -> (bx, by), bx <= by  (scalar loop, <=32 iters)
  int bid = blockIdx.x;
  int bx = 0, off = 0;
  while (bid >= off + (NCT - bx)) { off += NCT - bx; ++bx; }
  int by = bx + (bid - off);
  const bool diag = (bx == by);

  const int tid = threadIdx.x;
  const int lane = tid & 63;
  const int l15 = lane & 15;
  const int quad = lane >> 4;
  const int wave = tid >> 6;
  const int wi = (wave & 1) * 64;   // wave row offset in 128
  const int wj = (wave >> 1) * 64;  // wave col offset in 128
  const int rowBase = bx * 128;
  const int colBase = by * 128;
  const float invT = 1.0f / 0.07f;

  // stage both tiles: coalesced fp32 reads (16 threads sweep one row), f2bf,
  // swizzled ds_write (chunk (r,kc) -> kc*128+(r^kc); <=2-way banks = free)
  #pragma unroll
  for (int it = 0; it < 8; ++it) {
    int flat = it * 256 + tid;
    int r = flat >> 4, kc = flat & 15;
    const float* pa = feat + (size_t)(rowBase + r) * 256 + kc * 8;  // view0
    float4 a0 = *(const float4*)pa;
    float4 a1 = *(const float4*)(pa + 4);
    uint4 av;
    av.x = f2bf(a0.x) | (f2bf(a0.y) << 16);
    av.y = f2bf(a0.z) | (f2bf(a0.w) << 16);
    av.z = f2bf(a1.x) | (f2bf(a1.y) << 16);
    av.w = f2bf(a1.z) | (f2bf(a1.w) << 16);
    As[kc * 128 + (r ^ kc)] = av;
    const float* pb = feat + (size_t)(colBase + r) * 256 + kc * 8;
    float4 b0 = *(const float4*)pb;
    float4 b1 = *(const float4*)(pb + 4);
    uint4 bv;
    bv.x = f2bf(b0.x) | (f2bf(b0.y) << 16);
    bv.y = f2bf(b0.z) | (f2bf(b0.w) << 16);
    bv.z = f2bf(b1.x) | (f2bf(b1.y) << 16);
    bv.w = f2bf(b1.z) | (f2bf(b1.w) << 16);
    Bs[kc * 128 + (r ^ kc)] = bv;
  }
  if (tid < 128) {
    cLbS[tid] = Lb[colBase + tid];
    cRsS[tid] = rsv[colBase + tid];
  } else {
    int t = tid - 128;
    rLbS[t] = Lb[rowBase + t];
    rRsS[t] = rsv[rowBase + t];
  }
  __syncthreads();

  // exp references: ref = sum(bf16(f)^2) - 0.15 (lower bound on raw diag MFMA
  // dot; reassoc err ~1e-3). Identical op order for row/col -> bit-identical
  // for the same global row across all blocks.
  {
    int t = tid & 127;
    const uint4* src = (tid < 128) ? As : Bs;
    float s = 0.f;
    #pragma unroll
    for (int kc = 0; kc < 16; ++kc) {
      uint4 c = src[kc * 128 + (t ^ kc)];
      float v;
      v = bf2f(c.x & 0xffffu); s += v * v;
      v = bf2f(c.x >> 16);     s += v * v;
      v = bf2f(c.y & 0xffffu); s += v * v;
      v = bf2f(c.y >> 16);     s += v * v;
      v = bf2f(c.z & 0xffffu); s += v * v;
      v = bf2f(c.z >> 16);     s += v * v;
      v = bf2f(c.w & 0xffffu); s += v * v;
      v = bf2f(c.w >> 16);     s += v * v;
    }
    if (tid < 128) sS[t] = s - 0.15f;
    else sB[t] = s - 0.15f;
  }
  __syncthreads();

  float srow[16], scol[4];
  #pragma unroll
  for (int ti = 0; ti < 4; ++ti)
    #pragma unroll
    for (int r = 0; r < 4; ++r)
      srow[ti * 4 + r] = sS[wi + ti * 16 + quad * 4 + r];
  #pragma unroll
  for (int tj = 0; tj < 4; ++tj) scol[tj] = sB[wj + tj * 16 + l15];

  const bf16x8* Asv = (const bf16x8*)As;
  const bf16x8* Bsv = (const bf16x8*)Bs;

  f32x4 acc[4][4];
  #pragma unroll
  for (int ti = 0; ti < 4; ++ti)
    #pragma unroll
    for (int tj = 0; tj < 4; ++tj)
      acc[ti][tj] = (f32x4){0.f, 0.f, 0.f, 0.f};

  #pragma unroll
  for (int ks = 0; ks < 4; ++ks) {
    const int kc = ks * 4 + quad;
    const int abase = kc * 128 + wi + (l15 ^ kc);
    const int bbase = kc * 128 + wj + (l15 ^ kc);
    bf16x8 af[4], bfr[4];
    #pragma unroll
    for (int t = 0; t < 4; ++t) {
      af[t] = Asv[abase + t * 16];
      bfr[t] = Bsv[bbase + t * 16];
    }
    #pragma unroll
    for (int ti = 0; ti < 4; ++ti)
      #pragma unroll
      for (int tj = 0; tj < 4; ++tj)
        acc[ti][tj] = __builtin_amdgcn_mfma_f32_16x16x32_bf16(
            af[ti], bfr[tj], acc[ti][tj], 0, 0, 0);
  }

  // epilogue: C[row][col], row=wi+ti*16+quad*4+r, col=wj+tj*16+l15 (raw dots)
  float p_s[16], n_s[16], cp[4], cn[4], cmax[4];
  #pragma unroll
  for (int i = 0; i < 16; ++i) { p_s[i] = 0.f; n_s[i] = 0.f; }
  #pragma unroll
  for (int tj = 0; tj < 4; ++tj) { cp[tj] = 0.f; cn[tj] = 0.f; cmax[tj] = -1e30f; }

  #pragma unroll
  for (int ti = 0; ti < 4; ++ti)
    #pragma unroll
    for (int r = 0; r < 4; ++r) {
      int si = ti * 4 + r;
      float l0 = acc[ti][0][r], l1 = acc[ti][1][r];
      float l2 = acc[ti][2][r], l3 = acc[ti][3][r];
      cmax[0] = fmaxf(cmax[0], l0);
      cmax[1] = fmaxf(cmax[1], l1);
      cmax[2] = fmaxf(cmax[2], l2);
      cmax[3] = fmaxf(cmax[3], l3);
      float tm = fmaxf(fmaxf(l0, l1), fmaxf(l2, l3));
      if (tm > srow[si] - 6.3f) {  // row-side slow path (rare: ~diag only)
        int lrow = wi + ti * 16 + quad * 4 + r;
        uint4 la = rLbS[lrow];
        int ra = rRsS[lrow];
        float p = p_s[si], n = n_s[si];
        float lv[4] = {l0, l1, l2, l3};
        #pragma unroll
        for (int tj = 0; tj < 4; ++tj) {
          float e = __expf((lv[tj] - srow[si]) * invT);
          int lcol = wj + tj * 16 + l15;
          uint4 lb = cLbS[lcol];
          int inter = __popc(la.x & lb.x) + __popc(la.y & lb.y) +
                      __popc(la.z & lb.z) + __popc(la.w & lb.w);
          if (3 * inter > ra + cRsS[lcol]) p += e; else n += e;  // sim>=0.5 exact
        }
        p_s[si] = p;
        n_s[si] = n;
      }
    }

  // col-side (transpose contribution) — off-diagonal tiles only
  if (!diag) {
    #pragma unroll
    for (int tj = 0; tj < 4; ++tj) {
      if (cmax[tj] > scol[tj] - 6.3f) {  // rare
        int lcol = wj + tj * 16 + l15;
        uint4 lb = cLbS[lcol];
        int rb = cRsS[lcol];
        float p = cp[tj], n = cn[tj];
        #pragma unroll
        for (int ti = 0; ti < 4; ++ti)
          #pragma unroll
          for (int r = 0; r < 4; ++r) {
            float e = __expf((acc[ti][tj][r] - scol[tj]) * invT);
            int lrow = wi + ti * 16 + quad * 4 + r;
            uint4 la = rLbS[lrow];
            int inter = __popc(la.x & lb.x) + __popc(la.y & lb.y) +
                        __popc(la.z & lb.z) + __popc(la.w & lb.w);
            if (3 * inter > rRsS[lrow] + rb) p += e; else n += e;
          }
        cp[tj] = p;
        cn[tj] = n;
      }
    }
  }

  // row-side: sum across the 16 lanes (same quad) sharing each row
  #pragma unroll
  for (int si = 0; si < 16; ++si) {
    float p = p_s[si], n = n_s[si];
    #pragma unroll
    for (int o = 8; o >= 1; o >>= 1) {
      p += __shfl_xor(p, o);
      n += __shfl_xor(n, o);
    }
    p_s[si] = p;
    n_s[si] = n;
  }
  // col-side: sum across the 4 quads sharing each column
  #pragma unroll
  for (int tj = 0; tj < 4; ++tj) {
    float p = cp[tj], n = cn[tj];
    p += __shfl_xor(p, 16); n += __shfl_xor(n, 16);
    p += __shfl_xor(p, 32); n += __shfl_xor(n, 32);
    cp[tj] = p;
    cn[tj] = n;
  }

  // cross-wave merges via LDS (As dead; mrow 1 KB, mcol next 1 KB)
  __syncthreads();
  float* mrow = (float*)As;
  float* mcol = ((float*)As) + 256;
  if (wj == 64 && l15 == 0) {  // waves 2,3: row partials
    #pragma unroll
    for (int ti = 0; ti < 4; ++ti)
      #pragma unroll
      for (int r = 0; r < 4; ++r) {
        int row = wi + ti * 16 + quad * 4 + r;
        int si = ti * 4 + r;
        mrow[row * 2 + 0] = p_s[si];
        mrow[row * 2 + 1] = n_s[si];
      }
  }
  if (!diag && wi == 64 && quad == 0) {  // waves 1,3: col partials
    #pragma unroll
    for (int tj = 0; tj < 4; ++tj) {
      int col = wj + tj * 16 + l15;
      mcol[col * 2 + 0] = cp[tj];
      mcol[col * 2 + 1] = cn[tj];
    }
  }
  __syncthreads();
  if (wj == 0 && l15 == 0) {  // waves 0,1: row final -> slot part[by][...]
    #pragma unroll
    for (int ti = 0; ti < 4; ++ti)
      #pragma unroll
      for (int r = 0; r < 4; ++r) {
        int row = wi + ti * 16 + quad * 4 + r;
        int si = ti * 4 + r;
        float p = p_s[si] + mrow[row * 2 + 0];
        float n = n_s[si] + mrow[row * 2 + 1];
        part[(size_t)by * B_ROWS + rowBase + row] = make_float2(p, n);
      }
  }
  if (!diag && wi == 0 && quad == 0) {  // waves 0,2: col final -> part[bx][...]
    #pragma unroll
    for (int tj = 0; tj < 4; ++tj) {
      int col = wj + tj * 16 + l15;
      float p = cp[tj] + mcol[col * 2 + 0];
      float n = cn[tj] + mcol[col * 2 + 1];
      part[(size_t)bx * B_ROWS + colBase + col] = make_float2(p, n);
    }
  }
}

// 16 blocks x 256: one row per thread, 32 slot loads, per-row loss, wave
// reduction, one atomic per wave.
__global__ void merge_kernel(const float2* __restrict__ part,
                             const int* __restrict__ rsv,
                             float* __restrict__ accum) {
  int row = blockIdx.x * 256 + threadIdx.x;
  float p = 0.f, n = 0.f;
  #pragma unroll
  for (int c = 0; c < NCT; ++c) {
    float2 v = part[(size_t)c * B_ROWS + row];
    p += v.x;
    n += v.y;
  }
  float per = 0.f, cnt = 0.f;
  if (rsv[row] > 0) {  // exact: has_pos <=> row_sum > 0
    per = -logf(p / (p + n));
    cnt = 1.f;
  }
  #pragma unroll
  for (int o = 32; o >= 1; o >>= 1) {
    per += __shfl_xor(per, o);
    cnt += __shfl_xor(cnt, o);
  }
  if ((threadIdx.x & 63) == 0) {
    atomicAdd(accum + 0, per);
    atomicAdd(accum + 1, cnt);
  }
}

__global__ void fin_kernel(const float* __restrict__ accum,
                           float* __restrict__ out) {
  out[0] = accum[0] / fmaxf(accum[1], 1.0f);
}

extern "C" void kernel_launch(void* const* d_in, const int* in_sizes, int n_in,
                              void* d_out, int out_size, void* d_ws, size_t ws_size,
                              hipStream_t stream) {
  const float* feat = (const float*)d_in[0];
  const float* labels = (const float*)d_in[1];
  float* out = (float*)d_out;
  char* ws = (char*)d_ws;
  // workspace (~1.1 MB):
  uint4* Lbm = (uint4*)(ws + 0);            // 64 KB label masks
  int* rsv = (int*)(ws + 65536);            // 16 KB row sums
  float2* part = (float2*)(ws + 81920);     // 1 MB partials (32 x 4096)
  float* accum = (float*)(ws + 81920 + 1048576);  // 8 B

  hipLaunchKernelGGL(label_kernel, dim3(1024), dim3(256), 0, stream,
                     labels, Lbm, rsv, accum);
  hipLaunchKernelGGL(main_kernel, dim3(NTRI), dim3(256), 0, stream,
                     feat, Lbm, rsv, part);
  hipLaunchKernelGGL(merge_kernel, dim3(B_ROWS / 256), dim3(256), 0, stream,
                     part, rsv, accum);
  hipLaunchKernelGGL(fin_kernel, dim3(1), dim3(1), 0, stream, accum, out);
}